// Round 13
// baseline (135.648 us; speedup 1.0000x reference)
//
#include <hip/hip_runtime.h>
#include <hip/hip_bf16.h>

#define TEMP_INV (1.0f / 0.07f)
#define LOG2E 1.4426950408889634f
#define LN2 0.6931471805599453f
#define CFIX 21.0f

typedef __attribute__((ext_vector_type(4))) float f32x4;
typedef __attribute__((ext_vector_type(8))) int i32x8;

__device__ __forceinline__ void gload16(const unsigned char* g,
                                        unsigned char* l) {
  __builtin_amdgcn_global_load_lds(
      (const __attribute__((address_space(1))) void*)g,
      (__attribute__((address_space(3))) void*)l, 16, 0, 0);
}

// ---------------- Kernel 1: L2-normalize -> fp8(e4m3) feats x16, cross, ------
// ---------------- zero lsum (folded). Verbatim R12 (proven). -----------------
__global__ __launch_bounds__(256) void norm_kernel(
    const float* __restrict__ A, const float* __restrict__ P,
    unsigned char* __restrict__ F, float* __restrict__ cross,
    float* __restrict__ lsum, int B, int D) {
  const int row = blockIdx.x;
  const int t = threadIdx.x;
  {
    const int zi = row * 256 + t;
    if (zi < 2 * B) lsum[zi] = 0.f;
  }
  const float4* a4 = reinterpret_cast<const float4*>(A + (size_t)row * D);
  const float4* p4 = reinterpret_cast<const float4*>(P + (size_t)row * D);
  const int n4 = D >> 2;
  float sa = 0.f, sp = 0.f, sx = 0.f;
  for (int i = t; i < n4; i += 256) {
    float4 av = a4[i], pv = p4[i];
    sa += av.x * av.x + av.y * av.y + av.z * av.z + av.w * av.w;
    sp += pv.x * pv.x + pv.y * pv.y + pv.z * pv.z + pv.w * pv.w;
    sx += av.x * pv.x + av.y * pv.y + av.z * pv.z + av.w * pv.w;
  }
#pragma unroll
  for (int off = 32; off; off >>= 1) {
    sa += __shfl_down(sa, off);
    sp += __shfl_down(sp, off);
    sx += __shfl_down(sx, off);
  }
  __shared__ float red[3][4];
  const int wid = t >> 6, lane = t & 63;
  if (lane == 0) { red[0][wid] = sa; red[1][wid] = sp; red[2][wid] = sx; }
  __syncthreads();
  sa = red[0][0] + red[0][1] + red[0][2] + red[0][3];
  sp = red[1][0] + red[1][1] + red[1][2] + red[1][3];
  sx = red[2][0] + red[2][1] + red[2][2] + red[2][3];
  const float ian = rsqrtf(sa), ipn = rsqrtf(sp);
  const float ia = ian * 16.f, ip = ipn * 16.f;  // x16 -> e4m3 range
  unsigned char* fa = F + (size_t)row * D;
  unsigned char* fp = F + (size_t)(B + row) * D;
  for (int i = t; i < n4; i += 256) {
    float4 av = a4[i], pv = p4[i];
    int qa = 0, qp = 0;
    qa = __builtin_amdgcn_cvt_pk_fp8_f32(av.x * ia, av.y * ia, qa, false);
    qa = __builtin_amdgcn_cvt_pk_fp8_f32(av.z * ia, av.w * ia, qa, true);
    qp = __builtin_amdgcn_cvt_pk_fp8_f32(pv.x * ip, pv.y * ip, qp, false);
    qp = __builtin_amdgcn_cvt_pk_fp8_f32(pv.z * ip, pv.w * ip, qp, true);
    reinterpret_cast<int*>(fa)[i] = qa;
    reinterpret_cast<int*>(fp)[i] = qp;
  }
  if (t == 0) cross[row] = sx * ian * ipn;
}

// ---------------- Kernel 2: triangular fused Gram, MX-fp8 K=128 --------------
// 256x256 triangle tiles, FULL K=1024, 8 waves (2x4), 528 blocks x 1 tile.
// MFMA = mfma_scale_f32_16x16x128_f8f6f4, scales=127 (1.0) — numerics and
// per-lane-32B-contiguous-K operand layout PROVEN by R4 (passed, absmax 0).
// Pipeline (R9/R10-proven drain shape): per K-128 iter u:
//   {vmcnt(0); barrier; read frags(pair u&1); stage pair u+1 (8 gload16,
//    guarded); MFMA x32}.  2-pair ring = 128KB LDS; WAR-safe by barrier.
// Granule = K-64 sub-tile, 256 rows x 64B = 16KB. Layout: line=r>>1 (128B),
// chunk c=(r&1)*4+(k>>4), physical p=c^(line&7), byte=line*128+p*16+(k&15).
// Frag b128 reads: every consecutive 8-lane group covers all 8 bank-quads
// exactly once -> 0 conflicts by construction. Staging: linear dest, source
// carries inverse permutation (16B global-contiguous ✓).
#define UP 8  /* K-128 iters per tile */

__global__ __launch_bounds__(512, 2) void gram_lse_kernel(
    const unsigned char* __restrict__ F, float* __restrict__ lsum, int NN,
    int D) {
  __shared__ unsigned char lds8[2][2][2][16384];  // [pair][A/B][q][16KB]
  const int nrb = NN >> 8;
  const int ntri = nrb * (nrb + 1) / 2;  // 528
  int lin = blockIdx.x;
  lin = (lin & 7) * (ntri >> 3) + (lin >> 3);  // XCD swizzle (528 = 8*66)
  int by = (int)((sqrtf(8.f * (float)lin + 1.f) - 1.f) * 0.5f);
  while ((by + 1) * (by + 2) / 2 <= lin) ++by;
  while (by * (by + 1) / 2 > lin) --by;
  const int bx = lin - by * (by + 1) / 2;  // bx <= by
  const int r0 = bx * 256;  // i rows (B operand, N side)
  const int c0 = by * 256;  // j rows (A operand, M side)
  const bool diag = (bx == by);

  const int t = threadIdx.x;
  const int lane = t & 63, w = t >> 6;
  const int lo = lane & 15, hi = lane >> 4;
  const int wr = w >> 2, wn = w & 3;  // wr: j-half(128), wn: i-quarter(64)

  // ---- staging decode for physical chunks t and t+512 of a granule ----
  // ch -> line=ch>>3, p=ch&7, c=p^(line&7), r=(line<<1)|(c>>2), k16=c&3
  const int l0_ = t >> 3, c0_ = (t & 7) ^ (l0_ & 7);
  const int rS0 = (l0_ << 1) | (c0_ >> 2), kS0 = c0_ & 3;
  const int t1 = t + 512;
  const int l1_ = t1 >> 3, c1_ = (t1 & 7) ^ (l1_ & 7);
  const int rS1 = (l1_ << 1) | (c1_ >> 2), kS1 = c1_ & 3;
  const unsigned char* sA0 = F + (size_t)(c0 + rS0) * D + kS0 * 16;
  const unsigned char* sA1 = F + (size_t)(c0 + rS1) * D + kS1 * 16;
  const unsigned char* sB0 = F + (size_t)(r0 + rS0) * D + kS0 * 16;
  const unsigned char* sB1 = F + (size_t)(r0 + rS1) * D + kS1 * 16;
  const int dst0 = w * 1024;         // + lane*16 implicit (wave-uniform base)
  const int dst1 = 8192 + w * 1024;

  // ---- fragment read bases (byte offsets) ----
  // lane (lo,hi): region q=hi>>1; 32B = two b128 at p0*16 and (p0^1)*16
  const int p0 = (((lo & 1) << 2) | ((hi & 1) << 1)) ^ ((lo >> 1) & 7);
  const int rdA = (hi >> 1) * 16384 + wr * 8192 + (lo >> 1) * 128 + p0 * 16;
  const int rdA2 = rdA ^ 16;
  const int rdB = (hi >> 1) * 16384 + wn * 4096 + (lo >> 1) * 128 + p0 * 16;
  const int rdB2 = rdB ^ 16;

#define STAGE_PAIR(U, PB)                                            \
  do {                                                               \
    const int o0 = (2 * (U)) * 64, o1 = o0 + 64;                     \
    gload16(sA0 + o0, &lds8[PB][0][0][dst0]);                        \
    gload16(sA1 + o0, &lds8[PB][0][0][dst1]);                        \
    gload16(sA0 + o1, &lds8[PB][0][1][dst0]);                        \
    gload16(sA1 + o1, &lds8[PB][0][1][dst1]);                        \
    gload16(sB0 + o0, &lds8[PB][1][0][dst0]);                        \
    gload16(sB1 + o0, &lds8[PB][1][0][dst1]);                        \
    gload16(sB0 + o1, &lds8[PB][1][1][dst0]);                        \
    gload16(sB1 + o1, &lds8[PB][1][1][dst1]);                        \
  } while (0)

  f32x4 acc[8][4];
#pragma unroll
  for (int a = 0; a < 8; ++a)
#pragma unroll
    for (int bb = 0; bb < 4; ++bb) acc[a][bb] = (f32x4){0.f, 0.f, 0.f, 0.f};

  STAGE_PAIR(0, 0);  // prologue: 8 loads in flight

  for (int u = 0; u < UP; ++u) {
    const int pr = u & 1;
    asm volatile("s_waitcnt vmcnt(0)" ::: "memory");  // drain pair(u) stages
    __builtin_amdgcn_s_barrier();
    asm volatile("" ::: "memory");

    const unsigned char* RA = &lds8[pr][0][0][0];
    const unsigned char* RB = &lds8[pr][1][0][0];
    i32x8 bfr[4];
#pragma unroll
    for (int nf = 0; nf < 4; ++nf) {
      int4 q0 = *(const int4*)(RB + rdB + nf * 1024);
      int4 q1 = *(const int4*)(RB + rdB2 + nf * 1024);
      bfr[nf][0] = q0.x; bfr[nf][1] = q0.y; bfr[nf][2] = q0.z;
      bfr[nf][3] = q0.w; bfr[nf][4] = q1.x; bfr[nf][5] = q1.y;
      bfr[nf][6] = q1.z; bfr[nf][7] = q1.w;
    }

    if (u + 1 < UP) STAGE_PAIR(u + 1, pr ^ 1);  // guarded (no stale tail)

    __builtin_amdgcn_s_setprio(1);
#pragma unroll
    for (int mf = 0; mf < 8; ++mf) {
      int4 q0 = *(const int4*)(RA + rdA + mf * 1024);
      int4 q1 = *(const int4*)(RA + rdA2 + mf * 1024);
      i32x8 af;
      af[0] = q0.x; af[1] = q0.y; af[2] = q0.z; af[3] = q0.w;
      af[4] = q1.x; af[5] = q1.y; af[6] = q1.z; af[7] = q1.w;
#pragma unroll
      for (int nf = 0; nf < 4; ++nf)
        acc[mf][nf] = __builtin_amdgcn_mfma_scale_f32_16x16x128_f8f6f4(
            af, bfr[nf], acc[mf][nf], 0, 0, 0, 127, 0, 127);
    }
    __builtin_amdgcn_s_setprio(0);
    asm volatile("" ::: "memory");
  }

  // ---- dual-side epilogue (verbatim mapping, proven R4/R6-R12) ----
  // acc[mf][nf][rg]: j = c0 + wr*128 + mf*16 + hi*4 + rg
  //                  i = r0 + wn*64 + nf*16 + lo
  const float scl = LOG2E * TEMP_INV / 256.f;  // descale x16*x16
  float s_i[4] = {0.f, 0.f, 0.f, 0.f};
  float s_j[32];
#pragma unroll
  for (int q = 0; q < 32; ++q) s_j[q] = 0.f;
  {
    const int jb2 = c0 + wr * 128;
#pragma unroll
    for (int nf = 0; nf < 4; ++nf) {
      const int dg = (r0 + wn * 64 + nf * 16 + lo) - jb2;
#pragma unroll
      for (int mf = 0; mf < 8; ++mf)
#pragma unroll
        for (int rg = 0; rg < 4; ++rg) {
          const int jloc = mf * 16 + hi * 4 + rg;
          float e = exp2f(acc[mf][nf][rg] * scl - CFIX);
          if (diag && dg == jloc) e = 0.f;
          s_i[nf] += e;
          s_j[mf * 4 + rg] += e;
        }
    }
  }
#pragma unroll
  for (int nf = 0; nf < 4; ++nf) {
    float v = s_i[nf];
    v += __shfl_xor(v, 16);
    v += __shfl_xor(v, 32);
    if (hi == 0) atomicAdd(&lsum[r0 + wn * 64 + nf * 16 + lo], v);
  }
  if (!diag) {
#pragma unroll
    for (int q = 0; q < 32; ++q) {
      float v = s_j[q];
      v += __shfl_xor(v, 1);
      v += __shfl_xor(v, 2);
      v += __shfl_xor(v, 4);
      v += __shfl_xor(v, 8);
      if (lo == 0)
        atomicAdd(&lsum[c0 + wr * 128 + (q >> 2) * 16 + hi * 4 + (q & 3)], v);
    }
  }
#undef STAGE_PAIR
}

// ---------------- Kernel 3a: per-row loss -> per-block partial sums ----------
__global__ __launch_bounds__(256) void finalize_part(
    const float* __restrict__ lsum, const float* __restrict__ cross,
    const int* __restrict__ labels, float* __restrict__ bsum,
    float* __restrict__ bcnt, int B) {
  const int NN = 2 * B;
  const int i = blockIdx.x * 256 + threadIdx.x;
  float sum = 0.f, cnt = 0.f;
  if (i < NN) {
    const float lse = LN2 * (CFIX + log2f(lsum[i]));
    const float lab = (float)labels[i % B];
    sum = (lse - cross[i % B] * TEMP_INV) * lab;
    cnt = lab;
  }
#pragma unroll
  for (int off = 32; off; off >>= 1) {
    sum += __shfl_down(sum, off);
    cnt += __shfl_down(cnt, off);
  }
  __shared__ float rs[4], rc[4];
  const int wid = threadIdx.x >> 6, lane = threadIdx.x & 63;
  if (lane == 0) { rs[wid] = sum; rc[wid] = cnt; }
  __syncthreads();
  if (threadIdx.x == 0) {
    bsum[blockIdx.x] = rs[0] + rs[1] + rs[2] + rs[3];
    bcnt[blockIdx.x] = rc[0] + rc[1] + rc[2] + rc[3];
  }
}

// ---------------- Kernel 3b: final reduce ------------------------------------
__global__ __launch_bounds__(64) void finalize_final(
    const float* __restrict__ bsum, const float* __restrict__ bcnt,
    float* __restrict__ out, int nb) {
  const int t = threadIdx.x;
  float s = (t < nb) ? bsum[t] : 0.f;
  float c = (t < nb) ? bcnt[t] : 0.f;
#pragma unroll
  for (int off = 32; off; off >>= 1) {
    s += __shfl_down(s, off);
    c += __shfl_down(c, off);
  }
  if (t == 0) out[0] = (c > 0.f) ? s / c : 0.f;
}

extern "C" void kernel_launch(void* const* d_in, const int* in_sizes, int n_in,
                              void* d_out, int out_size, void* d_ws, size_t ws_size,
                              hipStream_t stream) {
  const float* A = (const float*)d_in[0];
  const float* P = (const float*)d_in[1];
  const int* labels = (const int*)d_in[2];
  float* out = (float*)d_out;
  const int B = in_sizes[2];
  const int D = in_sizes[0] / B;
  const int NN = 2 * B;

  char* ws = (char*)d_ws;
  unsigned char* F = (unsigned char*)ws;
  size_t off = (size_t)NN * D;  // fp8: 1 B/elem
  off = (off + 255) & ~(size_t)255;
  float* cross = (float*)(ws + off);
  off += (size_t)B * sizeof(float);
  off = (off + 255) & ~(size_t)255;
  float* lsum = (float*)(ws + off);
  off += (size_t)NN * sizeof(float);
  off = (off + 255) & ~(size_t)255;
  float* bsum = (float*)(ws + off);
  off += 64 * sizeof(float);
  float* bcnt = (float*)(ws + off);

  norm_kernel<<<B, 256, 0, stream>>>(A, P, F, cross, lsum, B, D);
  const int nrb = NN >> 8;               // 32 row-panels of 256
  const int ntri = nrb * (nrb + 1) / 2;  // 528 triangle tiles
  gram_lse_kernel<<<ntri, 512, 0, stream>>>(F, lsum, NN, D);
  const int nb = (NN + 255) / 256;  // 32
  finalize_part<<<nb, 256, 0, stream>>>(lsum, cross, labels, bsum, bcnt, B);
  finalize_final<<<1, 64, 0, stream>>>(bsum, bcnt, out, nb);
}

// Round 14
// 116.109 us; speedup vs baseline: 1.1683x; 1.1683x over previous
//
#include <hip/hip_runtime.h>
#include <hip/hip_bf16.h>

#define TEMP_INV (1.0f / 0.07f)
#define LOG2E 1.4426950408889634f
#define LN2 0.6931471805599453f
#define CFIX 21.0f

typedef __attribute__((ext_vector_type(4))) float f32x4;

__device__ __forceinline__ void gload16(const unsigned char* g,
                                        unsigned char* l) {
  __builtin_amdgcn_global_load_lds(
      (const __attribute__((address_space(1))) void*)g,
      (__attribute__((address_space(3))) void*)l, 16, 0, 0);
}

// ---------------- Kernel 1: L2-normalize -> fp8(e4m3) feats x16, cross, ------
// ---------------- zero lsum (folded). Verbatim R12 (proven). -----------------
__global__ __launch_bounds__(256) void norm_kernel(
    const float* __restrict__ A, const float* __restrict__ P,
    unsigned char* __restrict__ F, float* __restrict__ cross,
    float* __restrict__ lsum, int B, int D) {
  const int row = blockIdx.x;
  const int t = threadIdx.x;
  {
    const int zi = row * 256 + t;
    if (zi < 2 * B) lsum[zi] = 0.f;
  }
  const float4* a4 = reinterpret_cast<const float4*>(A + (size_t)row * D);
  const float4* p4 = reinterpret_cast<const float4*>(P + (size_t)row * D);
  const int n4 = D >> 2;
  float sa = 0.f, sp = 0.f, sx = 0.f;
  for (int i = t; i < n4; i += 256) {
    float4 av = a4[i], pv = p4[i];
    sa += av.x * av.x + av.y * av.y + av.z * av.z + av.w * av.w;
    sp += pv.x * pv.x + pv.y * pv.y + pv.z * pv.z + pv.w * pv.w;
    sx += av.x * pv.x + av.y * pv.y + av.z * pv.z + av.w * pv.w;
  }
#pragma unroll
  for (int off = 32; off; off >>= 1) {
    sa += __shfl_down(sa, off);
    sp += __shfl_down(sp, off);
    sx += __shfl_down(sx, off);
  }
  __shared__ float red[3][4];
  const int wid = t >> 6, lane = t & 63;
  if (lane == 0) { red[0][wid] = sa; red[1][wid] = sp; red[2][wid] = sx; }
  __syncthreads();
  sa = red[0][0] + red[0][1] + red[0][2] + red[0][3];
  sp = red[1][0] + red[1][1] + red[1][2] + red[1][3];
  sx = red[2][0] + red[2][1] + red[2][2] + red[2][3];
  const float ian = rsqrtf(sa), ipn = rsqrtf(sp);
  const float ia = ian * 16.f, ip = ipn * 16.f;  // x16 -> e4m3 range
  unsigned char* fa = F + (size_t)row * D;
  unsigned char* fp = F + (size_t)(B + row) * D;
  for (int i = t; i < n4; i += 256) {
    float4 av = a4[i], pv = p4[i];
    int qa = 0, qp = 0;
    qa = __builtin_amdgcn_cvt_pk_fp8_f32(av.x * ia, av.y * ia, qa, false);
    qa = __builtin_amdgcn_cvt_pk_fp8_f32(av.z * ia, av.w * ia, qa, true);
    qp = __builtin_amdgcn_cvt_pk_fp8_f32(pv.x * ip, pv.y * ip, qp, false);
    qp = __builtin_amdgcn_cvt_pk_fp8_f32(pv.z * ip, pv.w * ip, qp, true);
    reinterpret_cast<int*>(fa)[i] = qa;
    reinterpret_cast<int*>(fp)[i] = qp;
  }
  if (t == 0) cross[row] = sx * ian * ipn;
}

// ---------------- Kernel 2: triangular fused Gram (fp8, overlap + tail-split)-
// Work pieces: 512 full tiles (256j x 256i, MFN=8) + 32 j-halves of the last
// 16 tiles (128j x 256i, MFN=4; R11-proven mapping). One kernel, branch on
// blockIdx. All pieces FULL K=1024 (K-split forbidden — R5).
// Per K-64 iter (R12 buffers/counts, REORDERED for LDS||MFMA overlap):
//   {vmcnt(8); barrier; read KS0+KS1 frags (24 b64); stage v+3 (4 loads,
//    clamped-uniform); MFMA KS0; MFMA KS1}
// Reads precede MFMAs -> LDS unit drains KS1 while matrix runs KS0; every
// read consumed before next barrier (lgkm via consumption, R12's own safety
// argument); stages 3 buffers ahead; clamped tail keeps vmcnt uniform.
// fp8 granule (R12-proven): 256(or 128) rows x 32 k = 8KB(4KB); line=r>>2;
// chunk c=(r&3)*2+(k>>4); phys p=c^(line&7); byte=line*128+p*16+(k&15).
template <int MFN>  // MFN=8: full 256j; MFN=4: half 128j
__device__ __forceinline__ void gram_body(
    unsigned char* LDS, const unsigned char* F, float* lsum, int D,
    int r0, int c0, bool diag) {
  const int t = threadIdx.x;
  const int lane = t & 63, w = t >> 6;
  const int lo = lane & 15, hi = lane >> 4;
  const int wr = w >> 2, wn = w & 3;  // wr: j-half, wn: i-quarter(64)

  // staging decode (R12-proven): chunk ci -> line=ci>>3, cu=(ci&7)^(line&7),
  // trow=line*4+(cu>>1), kc=(cu&1)*16
  const int ciA = t & (MFN * 64 - 1);  // MFN=4: waves 4-7 mirror 0-3
  const int lrA = ciA >> 3, cuA = (ciA & 7) ^ (lrA & 7);
  const int trA = lrA * 4 + (cuA >> 1), kcA = (cuA & 1) << 4;
  const int lrB = t >> 3, cuB = (t & 7) ^ (lrB & 7);
  const int trB = lrB * 4 + (cuB >> 1), kcB = (cuB & 1) << 4;
  const unsigned char* sA = F + (size_t)(c0 + trA) * D + kcA;
  const unsigned char* sB = F + (size_t)(r0 + trB) * D + kcB;
  const int dstA = (w % MFN) * 1024;  // wave-uniform
  const int dstB = w * 1024;

  // fragment read byte offsets (R12-proven formula)
  int offA[MFN], offB[4];
#pragma unroll
  for (int mf = 0; mf < MFN; ++mf) {
    const int r = wr * (MFN * 16) + mf * 16 + lo;
    const int lr = r >> 2;
    const int cu = ((r & 3) << 1) | (hi >> 1);
    offA[mf] = lr * 128 + ((cu ^ (lr & 7)) << 4) + ((hi & 1) << 3);
  }
#pragma unroll
  for (int nf = 0; nf < 4; ++nf) {
    const int r = wn * 64 + nf * 16 + lo;
    const int lr = r >> 2;
    const int cu = ((r & 3) << 1) | (hi >> 1);
    offB[nf] = lr * 128 + ((cu ^ (lr & 7)) << 4) + ((hi & 1) << 3);
  }

#define STAGE(V, KS)                                                       \
  do {                                                                    \
    int v_ = (V); if (v_ > 15) v_ = 15;                                   \
    const int o_ = v_ * 64 + (KS) * 32;                                   \
    gload16(sA + o_, LDS + ((V) & 3) * 32768 + (KS) * 8192 + dstA);       \
    gload16(sB + o_, LDS + ((V) & 3) * 32768 + 16384 + (KS) * 8192 + dstB); \
  } while (0)

  f32x4 acc[MFN][4];
#pragma unroll
  for (int a = 0; a < MFN; ++a)
#pragma unroll
    for (int bb = 0; bb < 4; ++bb) acc[a][bb] = (f32x4){0.f, 0.f, 0.f, 0.f};

  // prologue: tiles 0,1,2 staged (12 loads/thread in flight)
  STAGE(0, 0); STAGE(0, 1);
  STAGE(1, 0); STAGE(1, 1);
  STAGE(2, 0); STAGE(2, 1);

  for (int v = 0; v < 16; ++v) {
    const int buf = v & 3;
    asm volatile("s_waitcnt vmcnt(8)" ::: "memory");  // tile v landed
    __builtin_amdgcn_s_barrier();
    asm volatile("" ::: "memory");

    const unsigned char* RA0 = LDS + buf * 32768;
    const unsigned char* RA1 = RA0 + 8192;
    const unsigned char* RB0 = LDS + buf * 32768 + 16384;
    const unsigned char* RB1 = RB0 + 8192;
    long a0[MFN], a1[MFN], b0[4], b1[4];
#pragma unroll
    for (int nf = 0; nf < 4; ++nf) b0[nf] = *(const long*)(RB0 + offB[nf]);
#pragma unroll
    for (int mf = 0; mf < MFN; ++mf) a0[mf] = *(const long*)(RA0 + offA[mf]);
#pragma unroll
    for (int nf = 0; nf < 4; ++nf) b1[nf] = *(const long*)(RB1 + offB[nf]);
#pragma unroll
    for (int mf = 0; mf < MFN; ++mf) a1[mf] = *(const long*)(RA1 + offA[mf]);

    STAGE(v + 3, 0);
    STAGE(v + 3, 1);

    __builtin_amdgcn_s_setprio(1);
#pragma unroll
    for (int mf = 0; mf < MFN; ++mf)
#pragma unroll
      for (int nf = 0; nf < 4; ++nf)
        acc[mf][nf] = __builtin_amdgcn_mfma_f32_16x16x32_fp8_fp8(
            a0[mf], b0[nf], acc[mf][nf], 0, 0, 0);
#pragma unroll
    for (int mf = 0; mf < MFN; ++mf)
#pragma unroll
      for (int nf = 0; nf < 4; ++nf)
        acc[mf][nf] = __builtin_amdgcn_mfma_f32_16x16x32_fp8_fp8(
            a1[mf], b1[nf], acc[mf][nf], 0, 0, 0);
    __builtin_amdgcn_s_setprio(0);
    asm volatile("" ::: "memory");
  }

  // ---- dual-side epilogue (R12/R11-proven mapping) ----
  // acc[mf][nf][rg]: j = c0 + wr*(MFN*16) + mf*16 + hi*4 + rg
  //                  i = r0 + wn*64 + nf*16 + lo
  const float scl = LOG2E * TEMP_INV / 256.f;  // descale x16*x16
  float s_i[4] = {0.f, 0.f, 0.f, 0.f};
  float s_j[MFN * 4];
#pragma unroll
  for (int q = 0; q < MFN * 4; ++q) s_j[q] = 0.f;
  {
    const int jb2 = c0 + wr * (MFN * 16);
#pragma unroll
    for (int nf = 0; nf < 4; ++nf) {
      const int dg = (r0 + wn * 64 + nf * 16 + lo) - jb2;
#pragma unroll
      for (int mf = 0; mf < MFN; ++mf)
#pragma unroll
        for (int rg = 0; rg < 4; ++rg) {
          const int jloc = mf * 16 + hi * 4 + rg;
          float e = exp2f(acc[mf][nf][rg] * scl - CFIX);
          if (diag && dg == jloc) e = 0.f;
          s_i[nf] += e;
          s_j[mf * 4 + rg] += e;
        }
    }
  }
#pragma unroll
  for (int nf = 0; nf < 4; ++nf) {
    float v = s_i[nf];
    v += __shfl_xor(v, 16);
    v += __shfl_xor(v, 32);
    if (hi == 0) atomicAdd(&lsum[r0 + wn * 64 + nf * 16 + lo], v);
  }
  if (!diag) {
#pragma unroll
    for (int q = 0; q < MFN * 4; ++q) {
      float v = s_j[q];
      v += __shfl_xor(v, 1);
      v += __shfl_xor(v, 2);
      v += __shfl_xor(v, 4);
      v += __shfl_xor(v, 8);
      if (lo == 0)
        atomicAdd(&lsum[c0 + wr * (MFN * 16) + (q >> 2) * 16 + hi * 4 +
                        (q & 3)],
                  v);
    }
  }
  asm volatile("s_waitcnt vmcnt(0)" ::: "memory");  // drain stale tail stages
#undef STAGE
}

__global__ __launch_bounds__(512, 2) void gram_lse_kernel(
    const unsigned char* __restrict__ F, float* __restrict__ lsum, int NN,
    int D) {
  __shared__ unsigned char lds8[4][2][2][8192];  // 128 KB, R12 layout
  const int nrb = NN >> 8;
  const int ntri = nrb * (nrb + 1) / 2;  // 528
  const int nfull = ntri - 16;           // 512 full tiles
  const int bidx = blockIdx.x;
  int lin, c0extra = 0;
  bool half = false;
  if (bidx < nfull) {
    lin = bidx;
    if ((nfull & 7) == 0) lin = (bidx & 7) * (nfull >> 3) + (bidx >> 3);
  } else {
    const int idx = bidx - nfull;  // 0..31
    lin = nfull + (idx >> 1);
    c0extra = (idx & 1) * 128;
    half = true;
  }
  int by = (int)((sqrtf(8.f * (float)lin + 1.f) - 1.f) * 0.5f);
  while ((by + 1) * (by + 2) / 2 <= lin) ++by;
  while (by * (by + 1) / 2 > lin) --by;
  const int bx = lin - by * (by + 1) / 2;  // bx <= by
  const int r0 = bx * 256;
  const int c0 = by * 256 + c0extra;
  const bool diag = (bx == by);

  if (!half)
    gram_body<8>(&lds8[0][0][0][0], F, lsum, D, r0, c0, diag);
  else
    gram_body<4>(&lds8[0][0][0][0], F, lsum, D, r0, c0, diag);
}

// ---------------- Kernel 3a: per-row loss -> per-block partial sums ----------
__global__ __launch_bounds__(256) void finalize_part(
    const float* __restrict__ lsum, const float* __restrict__ cross,
    const int* __restrict__ labels, float* __restrict__ bsum,
    float* __restrict__ bcnt, int B) {
  const int NN = 2 * B;
  const int i = blockIdx.x * 256 + threadIdx.x;
  float sum = 0.f, cnt = 0.f;
  if (i < NN) {
    const float lse = LN2 * (CFIX + log2f(lsum[i]));
    const float lab = (float)labels[i % B];
    sum = (lse - cross[i % B] * TEMP_INV) * lab;
    cnt = lab;
  }
#pragma unroll
  for (int off = 32; off; off >>= 1) {
    sum += __shfl_down(sum, off);
    cnt += __shfl_down(cnt, off);
  }
  __shared__ float rs[4], rc[4];
  const int wid = threadIdx.x >> 6, lane = threadIdx.x & 63;
  if (lane == 0) { rs[wid] = sum; rc[wid] = cnt; }
  __syncthreads();
  if (threadIdx.x == 0) {
    bsum[blockIdx.x] = rs[0] + rs[1] + rs[2] + rs[3];
    bcnt[blockIdx.x] = rc[0] + rc[1] + rc[2] + rc[3];
  }
}

// ---------------- Kernel 3b: final reduce ------------------------------------
__global__ __launch_bounds__(64) void finalize_final(
    const float* __restrict__ bsum, const float* __restrict__ bcnt,
    float* __restrict__ out, int nb) {
  const int t = threadIdx.x;
  float s = (t < nb) ? bsum[t] : 0.f;
  float c = (t < nb) ? bcnt[t] : 0.f;
#pragma unroll
  for (int off = 32; off; off >>= 1) {
    s += __shfl_down(s, off);
    c += __shfl_down(c, off);
  }
  if (t == 0) out[0] = (c > 0.f) ? s / c : 0.f;
}

extern "C" void kernel_launch(void* const* d_in, const int* in_sizes, int n_in,
                              void* d_out, int out_size, void* d_ws, size_t ws_size,
                              hipStream_t stream) {
  const float* A = (const float*)d_in[0];
  const float* P = (const float*)d_in[1];
  const int* labels = (const int*)d_in[2];
  float* out = (float*)d_out;
  const int B = in_sizes[2];
  const int D = in_sizes[0] / B;
  const int NN = 2 * B;

  char* ws = (char*)d_ws;
  unsigned char* F = (unsigned char*)ws;
  size_t off = (size_t)NN * D;  // fp8: 1 B/elem
  off = (off + 255) & ~(size_t)255;
  float* cross = (float*)(ws + off);
  off += (size_t)B * sizeof(float);
  off = (off + 255) & ~(size_t)255;
  float* lsum = (float*)(ws + off);
  off += (size_t)NN * sizeof(float);
  off = (off + 255) & ~(size_t)255;
  float* bsum = (float*)(ws + off);
  off += 64 * sizeof(float);
  float* bcnt = (float*)(ws + off);

  norm_kernel<<<B, 256, 0, stream>>>(A, P, F, cross, lsum, B, D);
  const int nrb = NN >> 8;               // 32 row-panels of 256
  const int ntri = nrb * (nrb + 1) / 2;  // 528
  const int nblk = (ntri - 16) + 32;     // 512 full + 32 half blocks
  gram_lse_kernel<<<nblk, 512, 0, stream>>>(F, lsum, NN, D);
  const int nb = (NN + 255) / 256;  // 32
  finalize_part<<<nb, 256, 0, stream>>>(lsum, cross, labels, bsum, bcnt, B);
  finalize_final<<<1, 64, 0, stream>>>(bsum, bcnt, out, nb);
}

// Round 15
// 115.842 us; speedup vs baseline: 1.1710x; 1.0023x over previous
//
#include <hip/hip_runtime.h>
#include <hip/hip_bf16.h>

#define TEMP_INV (1.0f / 0.07f)
#define LOG2E 1.4426950408889634f
#define LN2 0.6931471805599453f
#define CFIX 21.0f

typedef __attribute__((ext_vector_type(4))) float f32x4;

__device__ __forceinline__ void gload16(const unsigned char* g,
                                        unsigned char* l) {
  __builtin_amdgcn_global_load_lds(
      (const __attribute__((address_space(1))) void*)g,
      (__attribute__((address_space(3))) void*)l, 16, 0, 0);
}

// ---------------- Kernel 1: L2-normalize -> fp8(e4m3) feats x16, cross, ------
// ---------------- zero lsum (folded). Verbatim R12 (proven). -----------------
__global__ __launch_bounds__(256) void norm_kernel(
    const float* __restrict__ A, const float* __restrict__ P,
    unsigned char* __restrict__ F, float* __restrict__ cross,
    float* __restrict__ lsum, int B, int D) {
  const int row = blockIdx.x;
  const int t = threadIdx.x;
  {
    const int zi = row * 256 + t;
    if (zi < 2 * B) lsum[zi] = 0.f;
  }
  const float4* a4 = reinterpret_cast<const float4*>(A + (size_t)row * D);
  const float4* p4 = reinterpret_cast<const float4*>(P + (size_t)row * D);
  const int n4 = D >> 2;
  float sa = 0.f, sp = 0.f, sx = 0.f;
  for (int i = t; i < n4; i += 256) {
    float4 av = a4[i], pv = p4[i];
    sa += av.x * av.x + av.y * av.y + av.z * av.z + av.w * av.w;
    sp += pv.x * pv.x + pv.y * pv.y + pv.z * pv.z + pv.w * pv.w;
    sx += av.x * pv.x + av.y * pv.y + av.z * pv.z + av.w * pv.w;
  }
#pragma unroll
  for (int off = 32; off; off >>= 1) {
    sa += __shfl_down(sa, off);
    sp += __shfl_down(sp, off);
    sx += __shfl_down(sx, off);
  }
  __shared__ float red[3][4];
  const int wid = t >> 6, lane = t & 63;
  if (lane == 0) { red[0][wid] = sa; red[1][wid] = sp; red[2][wid] = sx; }
  __syncthreads();
  sa = red[0][0] + red[0][1] + red[0][2] + red[0][3];
  sp = red[1][0] + red[1][1] + red[1][2] + red[1][3];
  sx = red[2][0] + red[2][1] + red[2][2] + red[2][3];
  const float ian = rsqrtf(sa), ipn = rsqrtf(sp);
  const float ia = ian * 16.f, ip = ipn * 16.f;  // x16 -> e4m3 range
  unsigned char* fa = F + (size_t)row * D;
  unsigned char* fp = F + (size_t)(B + row) * D;
  for (int i = t; i < n4; i += 256) {
    float4 av = a4[i], pv = p4[i];
    int qa = 0, qp = 0;
    qa = __builtin_amdgcn_cvt_pk_fp8_f32(av.x * ia, av.y * ia, qa, false);
    qa = __builtin_amdgcn_cvt_pk_fp8_f32(av.z * ia, av.w * ia, qa, true);
    qp = __builtin_amdgcn_cvt_pk_fp8_f32(pv.x * ip, pv.y * ip, qp, false);
    qp = __builtin_amdgcn_cvt_pk_fp8_f32(pv.z * ip, pv.w * ip, qp, true);
    reinterpret_cast<int*>(fa)[i] = qa;
    reinterpret_cast<int*>(fp)[i] = qp;
  }
  if (t == 0) cross[row] = sx * ian * ipn;
}

// =============== fp8 granule layout (R12-proven, 256 rows x 32 k = 8KB) ======
// line=r>>2; chunk c=(r&3)*2+(k>>4); phys p=c^(line&7);
// byte=line*128+p*16+(k&15). Frag-read formula proven absmax-0 in R12/R14.

// ---------------- Full-tile body: 8-phase fp8 (R10 schedule, counts halved) --
// Per stage = 1 gload16/thread (8KB region / 512 threads). vmcnt trace
// re-derived for 1-load stages: prologue vmcnt(3) [was 6], P4/P8 vmcnt(2)
// [was 4]. Coverage: every region read covered by a vmcnt >=1 phase earlier
// + barrier; overwrites land after consuming phase's closing barrier (R10's
// proven WAR argument). Clamped tail keeps per-wave counts uniform.
__device__ __forceinline__ void gram_full8(
    unsigned char* LDS, const unsigned char* F, float* lsum, int D,
    int r0, int c0, bool diag) {
  const int t = threadIdx.x;
  const int lane = t & 63, w = t >> 6;
  const int lo = lane & 15, hi = lane >> 4;
  const int wr = w >> 2, wn = w & 3;  // wr: j-half(128), wn: i-quarter(64)

  // staging decode: ci=t; line=ci>>3; p=ci&7; c=p^(line&7);
  // trow=line*4+(c>>1); kc=(c&1)*16
  const int lineS = t >> 3, cS = (t & 7) ^ (lineS & 7);
  const int trS = lineS * 4 + (cS >> 1), kcS = (cS & 1) << 4;
  const unsigned char* sA = F + (size_t)(c0 + trS) * D + kcS;
  const unsigned char* sB = F + (size_t)(r0 + trS) * D + kcS;
  const int dstW = w * 1024;  // wave-uniform byte base within a region

  // fragment read byte offsets (R12-proven)
  int offA[8], offB[4];
#pragma unroll
  for (int mf = 0; mf < 8; ++mf) {
    const int r = wr * 128 + mf * 16 + lo;
    const int lr = r >> 2;
    const int cu = ((r & 3) << 1) | (hi >> 1);
    offA[mf] = lr * 128 + ((cu ^ (lr & 7)) << 4) + ((hi & 1) << 3);
  }
#pragma unroll
  for (int nf = 0; nf < 4; ++nf) {
    const int r = wn * 64 + nf * 16 + lo;
    const int lr = r >> 2;
    const int cu = ((r & 3) << 1) | (hi >> 1);
    offB[nf] = lr * 128 + ((cu ^ (lr & 7)) << 4) + ((hi & 1) << 3);
  }

  // region(BUF, AB, KS) byte base: BUF*32768 + AB*16384 + KS*8192 (64KB used)
#define STAGE_A(T, KS, BUF)                                                 \
  do {                                                                      \
    int v_ = (T); if (v_ > 15) v_ = 15;                                     \
    gload16(sA + v_ * 64 + (KS) * 32,                                       \
            LDS + (BUF) * 32768 + (KS) * 8192 + dstW);                      \
  } while (0)
#define STAGE_B(T, KS, BUF)                                                 \
  do {                                                                      \
    int v_ = (T); if (v_ > 15) v_ = 15;                                     \
    gload16(sB + v_ * 64 + (KS) * 32,                                       \
            LDS + (BUF) * 32768 + 16384 + (KS) * 8192 + dstW);              \
  } while (0)

  f32x4 acc[8][4];
  long bfr[4];

#define PHASE(BUF, MH, KS, READB, STAGE_STMT, WAIT2)                          \
  do {                                                                        \
    const unsigned char* RA_ = LDS + (BUF) * 32768 + (KS) * 8192;             \
    const unsigned char* RB_ = RA_ + 16384;                                   \
    if (READB) {                                                              \
      _Pragma("unroll") for (int nf = 0; nf < 4; ++nf)                        \
          bfr[nf] = *(const long*)(RB_ + offB[nf]);                           \
    }                                                                         \
    long af[4];                                                               \
    _Pragma("unroll") for (int m = 0; m < 4; ++m)                             \
        af[m] = *(const long*)(RA_ + offA[(MH)*4 + m]);                       \
    STAGE_STMT;                                                               \
    if (WAIT2) asm volatile("s_waitcnt vmcnt(2)" ::: "memory");               \
    asm volatile("" ::: "memory");                                            \
    __builtin_amdgcn_s_barrier();                                             \
    asm volatile("" ::: "memory");                                            \
    __builtin_amdgcn_s_setprio(1);                                            \
    _Pragma("unroll") for (int m = 0; m < 4; ++m)                             \
      _Pragma("unroll") for (int nf = 0; nf < 4; ++nf)                        \
          acc[(MH)*4 + m][nf] = __builtin_amdgcn_mfma_f32_16x16x32_fp8_fp8(   \
              af[m], bfr[nf], acc[(MH)*4 + m][nf], 0, 0, 0);                  \
    __builtin_amdgcn_s_setprio(0);                                            \
    asm volatile("" ::: "memory");                                            \
    __builtin_amdgcn_s_barrier();                                             \
    asm volatile("" ::: "memory");                                            \
  } while (0)

#pragma unroll
  for (int a = 0; a < 8; ++a)
#pragma unroll
    for (int bb = 0; bb < 4; ++bb) acc[a][bb] = (f32x4){0.f, 0.f, 0.f, 0.f};

  // prologue: 7 regions (A1k1 staged by iter0's P1); vmcnt(3) drains buf0
  STAGE_A(0, 0, 0); STAGE_B(0, 0, 0);
  STAGE_A(0, 1, 0); STAGE_B(0, 1, 0);
  STAGE_A(1, 0, 1); STAGE_B(1, 0, 1);
  STAGE_B(1, 1, 1);
  asm volatile("s_waitcnt vmcnt(3)" ::: "memory");
  __builtin_amdgcn_s_barrier();
  asm volatile("" ::: "memory");

  for (int it = 0; it < 8; ++it) {
    const int tt = it * 2;  // even K-64 tile -> buf0; odd -> buf1
    PHASE(0, 0, 0, true,  STAGE_A(tt + 1, 1, 1), false);  // P1
    PHASE(0, 1, 0, false, STAGE_B(tt + 2, 0, 0), false);  // P2
    PHASE(0, 0, 1, true,  STAGE_A(tt + 2, 0, 0), false);  // P3
    PHASE(0, 1, 1, false, STAGE_B(tt + 2, 1, 0), true);   // P4 vmcnt(2)
    PHASE(1, 0, 0, true,  STAGE_A(tt + 2, 1, 0), false);  // P5
    PHASE(1, 1, 0, false, STAGE_B(tt + 3, 0, 1), false);  // P6
    PHASE(1, 0, 1, true,  STAGE_A(tt + 3, 0, 1), false);  // P7
    PHASE(1, 1, 1, false, STAGE_B(tt + 3, 1, 1), true);   // P8 vmcnt(2)
  }

  // ---- dual-side epilogue (R12/R14-proven mapping) ----
  const float scl = LOG2E * TEMP_INV / 256.f;
  float s_i[4] = {0.f, 0.f, 0.f, 0.f};
  float s_j[32];
#pragma unroll
  for (int q = 0; q < 32; ++q) s_j[q] = 0.f;
  {
    const int jb2 = c0 + wr * 128;
#pragma unroll
    for (int nf = 0; nf < 4; ++nf) {
      const int dg = (r0 + wn * 64 + nf * 16 + lo) - jb2;
#pragma unroll
      for (int mf = 0; mf < 8; ++mf)
#pragma unroll
        for (int rg = 0; rg < 4; ++rg) {
          const int jloc = mf * 16 + hi * 4 + rg;
          float e = exp2f(acc[mf][nf][rg] * scl - CFIX);
          if (diag && dg == jloc) e = 0.f;
          s_i[nf] += e;
          s_j[mf * 4 + rg] += e;
        }
    }
  }
#pragma unroll
  for (int nf = 0; nf < 4; ++nf) {
    float v = s_i[nf];
    v += __shfl_xor(v, 16);
    v += __shfl_xor(v, 32);
    if (hi == 0) atomicAdd(&lsum[r0 + wn * 64 + nf * 16 + lo], v);
  }
  if (!diag) {
#pragma unroll
    for (int q = 0; q < 32; ++q) {
      float v = s_j[q];
      v += __shfl_xor(v, 1);
      v += __shfl_xor(v, 2);
      v += __shfl_xor(v, 4);
      v += __shfl_xor(v, 8);
      if (lo == 0)
        atomicAdd(&lsum[c0 + wr * 128 + (q >> 2) * 16 + hi * 4 + (q & 3)], v);
    }
  }
  asm volatile("s_waitcnt vmcnt(0)" ::: "memory");  // drain clamped tail
#undef PHASE
#undef STAGE_A
#undef STAGE_B
}

// ---------------- Half-tile body (MFN=4): R14's proven single-barrier loop ---
__device__ __forceinline__ void gram_half(
    unsigned char* LDS, const unsigned char* F, float* lsum, int D,
    int r0, int c0, bool diag) {
  const int MFN = 4;
  const int t = threadIdx.x;
  const int lane = t & 63, w = t >> 6;
  const int lo = lane & 15, hi = lane >> 4;
  const int wr = w >> 2, wn = w & 3;

  const int ciA = t & (MFN * 64 - 1);
  const int lrA = ciA >> 3, cuA = (ciA & 7) ^ (lrA & 7);
  const int trA = lrA * 4 + (cuA >> 1), kcA = (cuA & 1) << 4;
  const int lrB = t >> 3, cuB = (t & 7) ^ (lrB & 7);
  const int trB = lrB * 4 + (cuB >> 1), kcB = (cuB & 1) << 4;
  const unsigned char* sA = F + (size_t)(c0 + trA) * D + kcA;
  const unsigned char* sB = F + (size_t)(r0 + trB) * D + kcB;
  const int dstA = (w % MFN) * 1024;
  const int dstB = w * 1024;

  int offA[MFN], offB[4];
#pragma unroll
  for (int mf = 0; mf < MFN; ++mf) {
    const int r = wr * (MFN * 16) + mf * 16 + lo;
    const int lr = r >> 2;
    const int cu = ((r & 3) << 1) | (hi >> 1);
    offA[mf] = lr * 128 + ((cu ^ (lr & 7)) << 4) + ((hi & 1) << 3);
  }
#pragma unroll
  for (int nf = 0; nf < 4; ++nf) {
    const int r = wn * 64 + nf * 16 + lo;
    const int lr = r >> 2;
    const int cu = ((r & 3) << 1) | (hi >> 1);
    offB[nf] = lr * 128 + ((cu ^ (lr & 7)) << 4) + ((hi & 1) << 3);
  }

#define STAGE(V, KS)                                                        \
  do {                                                                      \
    int v_ = (V); if (v_ > 15) v_ = 15;                                     \
    const int o_ = v_ * 64 + (KS) * 32;                                     \
    gload16(sA + o_, LDS + ((V) & 3) * 32768 + (KS) * 8192 + dstA);         \
    gload16(sB + o_, LDS + ((V) & 3) * 32768 + 16384 + (KS) * 8192 + dstB); \
  } while (0)

  f32x4 acc[MFN][4];
#pragma unroll
  for (int a = 0; a < MFN; ++a)
#pragma unroll
    for (int bb = 0; bb < 4; ++bb) acc[a][bb] = (f32x4){0.f, 0.f, 0.f, 0.f};

  STAGE(0, 0); STAGE(0, 1);
  STAGE(1, 0); STAGE(1, 1);
  STAGE(2, 0); STAGE(2, 1);

  for (int v = 0; v < 16; ++v) {
    const int buf = v & 3;
    asm volatile("s_waitcnt vmcnt(8)" ::: "memory");
    __builtin_amdgcn_s_barrier();
    asm volatile("" ::: "memory");

    const unsigned char* RA0 = LDS + buf * 32768;
    const unsigned char* RA1 = RA0 + 8192;
    const unsigned char* RB0 = RA0 + 16384;
    const unsigned char* RB1 = RB0 + 8192;
    long a0[MFN], a1[MFN], b0[4], b1[4];
#pragma unroll
    for (int nf = 0; nf < 4; ++nf) b0[nf] = *(const long*)(RB0 + offB[nf]);
#pragma unroll
    for (int mf = 0; mf < MFN; ++mf) a0[mf] = *(const long*)(RA0 + offA[mf]);
#pragma unroll
    for (int nf = 0; nf < 4; ++nf) b1[nf] = *(const long*)(RB1 + offB[nf]);
#pragma unroll
    for (int mf = 0; mf < MFN; ++mf) a1[mf] = *(const long*)(RA1 + offA[mf]);

    STAGE(v + 3, 0);
    STAGE(v + 3, 1);

    __builtin_amdgcn_s_setprio(1);
#pragma unroll
    for (int mf = 0; mf < MFN; ++mf)
#pragma unroll
      for (int nf = 0; nf < 4; ++nf)
        acc[mf][nf] = __builtin_amdgcn_mfma_f32_16x16x32_fp8_fp8(
            a0[mf], b0[nf], acc[mf][nf], 0, 0, 0);
#pragma unroll
    for (int mf = 0; mf < MFN; ++mf)
#pragma unroll
      for (int nf = 0; nf < 4; ++nf)
        acc[mf][nf] = __builtin_amdgcn_mfma_f32_16x16x32_fp8_fp8(
            a1[mf], b1[nf], acc[mf][nf], 0, 0, 0);
    __builtin_amdgcn_s_setprio(0);
    asm volatile("" ::: "memory");
  }

  const float scl = LOG2E * TEMP_INV / 256.f;
  float s_i[4] = {0.f, 0.f, 0.f, 0.f};
  float s_j[MFN * 4];
#pragma unroll
  for (int q = 0; q < MFN * 4; ++q) s_j[q] = 0.f;
  {
    const int jb2 = c0 + wr * (MFN * 16);
#pragma unroll
    for (int nf = 0; nf < 4; ++nf) {
      const int dg = (r0 + wn * 64 + nf * 16 + lo) - jb2;
#pragma unroll
      for (int mf = 0; mf < MFN; ++mf)
#pragma unroll
        for (int rg = 0; rg < 4; ++rg) {
          const int jloc = mf * 16 + hi * 4 + rg;
          float e = exp2f(acc[mf][nf][rg] * scl - CFIX);
          if (diag && dg == jloc) e = 0.f;
          s_i[nf] += e;
          s_j[mf * 4 + rg] += e;
        }
    }
  }
#pragma unroll
  for (int nf = 0; nf < 4; ++nf) {
    float v = s_i[nf];
    v += __shfl_xor(v, 16);
    v += __shfl_xor(v, 32);
    if (hi == 0) atomicAdd(&lsum[r0 + wn * 64 + nf * 16 + lo], v);
  }
  if (!diag) {
#pragma unroll
    for (int q = 0; q < MFN * 4; ++q) {
      float v = s_j[q];
      v += __shfl_xor(v, 1);
      v += __shfl_xor(v, 2);
      v += __shfl_xor(v, 4);
      v += __shfl_xor(v, 8);
      if (lo == 0)
        atomicAdd(&lsum[c0 + wr * (MFN * 16) + (q >> 2) * 16 + hi * 4 +
                        (q & 3)],
                  v);
    }
  }
  asm volatile("s_waitcnt vmcnt(0)" ::: "memory");
#undef STAGE
}

__global__ __launch_bounds__(512, 2) void gram_lse_kernel(
    const unsigned char* __restrict__ F, float* __restrict__ lsum, int NN,
    int D) {
  __shared__ unsigned char lds8[4][32768];  // 128 KB (full body uses 64 KB)
  const int nrb = NN >> 8;
  const int ntri = nrb * (nrb + 1) / 2;  // 528
  const int nfull = ntri - 16;           // 512 full tiles
  const int bidx = blockIdx.x;
  int lin, c0extra = 0;
  bool half = false;
  if (bidx < nfull) {
    lin = bidx;
    if ((nfull & 7) == 0) lin = (bidx & 7) * (nfull >> 3) + (bidx >> 3);
  } else {
    const int idx = bidx - nfull;  // 0..31
    lin = nfull + (idx >> 1);
    c0extra = (idx & 1) * 128;
    half = true;
  }
  int by = (int)((sqrtf(8.f * (float)lin + 1.f) - 1.f) * 0.5f);
  while ((by + 1) * (by + 2) / 2 <= lin) ++by;
  while (by * (by + 1) / 2 > lin) --by;
  const int bx = lin - by * (by + 1) / 2;  // bx <= by
  const int r0 = bx * 256;
  const int c0 = by * 256 + c0extra;
  const bool diag = (bx == by);

  if (!half)
    gram_full8(&lds8[0][0], F, lsum, D, r0, c0, diag);
  else
    gram_half(&lds8[0][0], F, lsum, D, r0, c0, diag);
}

// ---------------- Kernel 3a: per-row loss -> per-block partial sums ----------
__global__ __launch_bounds__(256) void finalize_part(
    const float* __restrict__ lsum, const float* __restrict__ cross,
    const int* __restrict__ labels, float* __restrict__ bsum,
    float* __restrict__ bcnt, int B) {
  const int NN = 2 * B;
  const int i = blockIdx.x * 256 + threadIdx.x;
  float sum = 0.f, cnt = 0.f;
  if (i < NN) {
    const float lse = LN2 * (CFIX + log2f(lsum[i]));
    const float lab = (float)labels[i % B];
    sum = (lse - cross[i % B] * TEMP_INV) * lab;
    cnt = lab;
  }
#pragma unroll
  for (int off = 32; off; off >>= 1) {
    sum += __shfl_down(sum, off);
    cnt += __shfl_down(cnt, off);
  }
  __shared__ float rs[4], rc[4];
  const int wid = threadIdx.x >> 6, lane = threadIdx.x & 63;
  if (lane == 0) { rs[wid] = sum; rc[wid] = cnt; }
  __syncthreads();
  if (threadIdx.x == 0) {
    bsum[blockIdx.x] = rs[0] + rs[1] + rs[2] + rs[3];
    bcnt[blockIdx.x] = rc[0] + rc[1] + rc[2] + rc[3];
  }
}

// ---------------- Kernel 3b: final reduce ------------------------------------
__global__ __launch_bounds__(64) void finalize_final(
    const float* __restrict__ bsum, const float* __restrict__ bcnt,
    float* __restrict__ out, int nb) {
  const int t = threadIdx.x;
  float s = (t < nb) ? bsum[t] : 0.f;
  float c = (t < nb) ? bcnt[t] : 0.f;
#pragma unroll
  for (int off = 32; off; off >>= 1) {
    s += __shfl_down(s, off);
    c += __shfl_down(c, off);
  }
  if (t == 0) out[0] = (c > 0.f) ? s / c : 0.f;
}

extern "C" void kernel_launch(void* const* d_in, const int* in_sizes, int n_in,
                              void* d_out, int out_size, void* d_ws, size_t ws_size,
                              hipStream_t stream) {
  const float* A = (const float*)d_in[0];
  const float* P = (const float*)d_in[1];
  const int* labels = (const int*)d_in[2];
  float* out = (float*)d_out;
  const int B = in_sizes[2];
  const int D = in_sizes[0] / B;
  const int NN = 2 * B;

  char* ws = (char*)d_ws;
  unsigned char* F = (unsigned char*)ws;
  size_t off = (size_t)NN * D;  // fp8: 1 B/elem
  off = (off + 255) & ~(size_t)255;
  float* cross = (float*)(ws + off);
  off += (size_t)B * sizeof(float);
  off = (off + 255) & ~(size_t)255;
  float* lsum = (float*)(ws + off);
  off += (size_t)NN * sizeof(float);
  off = (off + 255) & ~(size_t)255;
  float* bsum = (float*)(ws + off);
  off += 64 * sizeof(float);
  float* bcnt = (float*)(ws + off);

  norm_kernel<<<B, 256, 0, stream>>>(A, P, F, cross, lsum, B, D);
  const int nrb = NN >> 8;               // 32 row-panels of 256
  const int ntri = nrb * (nrb + 1) / 2;  // 528
  const int nblk = (ntri - 16) + 32;     // 512 full + 32 half blocks
  gram_lse_kernel<<<nblk, 512, 0, stream>>>(F, lsum, NN, D);
  const int nb = (NN + 255) / 256;  // 32
  finalize_part<<<nb, 256, 0, stream>>>(lsum, cross, labels, bsum, bcnt, B);
  finalize_final<<<1, 64, 0, stream>>>(bsum, bcnt, out, nb);
}